// Round 20
// baseline (619.867 us; speedup 1.0000x reference)
//
#include <hip/hip_runtime.h>

#define NHID 128
#define NHEAD 8
#define NNODE 100000
#define NEDGE 500000
#define NEG 0.2f
#define SCORE_GRID 512
#define GEMM_GRID 512
#define AGG_BLOCKS 6250    // 16 nodes per block (4 waves x 4 nodes)
#define EB ((NEDGE + 255) / 256)
#define SB ((NNODE + 1023) / 1024)

typedef float4 f4;
typedef __attribute__((ext_vector_type(8))) short bfrag;   // 8 bf16 (4 VGPR)
typedef __attribute__((ext_vector_type(4))) float facc;    // 4 f32 acc

__device__ inline float b2f(unsigned int u) {
    return __uint_as_float(u << 16);
}
__device__ inline unsigned short f2b(float f) {
    unsigned int u = __float_as_uint(f);
    unsigned int r = (u + 0x7FFFu + ((u >> 16) & 1u)) >> 16;
    return (unsigned short)r;
}
__device__ inline float fast_tanh(float x) {
    float e = __expf(2.f * x);
    return 1.f - 2.f / (e + 1.f);
}

// ---- prep fused: weight transposes + G-matrices + dst hist ----
struct WavSet {
    const float* W; const float* b;
    const float* v0; const float* v1; const float* v2; const float* v3;
    ushort* GT; float* bAv;
};

__global__ __launch_bounds__(256) void prep_fused(
    const float* __restrict__ w0, const float* __restrict__ w1,
    const float* __restrict__ w2, const float* __restrict__ w3,
    const float* __restrict__ w4, const float* __restrict__ w5,
    ushort* __restrict__ o0, ushort* __restrict__ o1,
    ushort* __restrict__ o2, ushort* __restrict__ o3,
    ushort* __restrict__ o4, ushort* __restrict__ o5,
    WavSet s0, WavSet s1, WavSet s2, WavSet s3,
    const int* __restrict__ e0, const int* __restrict__ e1,
    const int* __restrict__ e2, int* __restrict__ deg3)
{
    const int b = blockIdx.x;
    if (b < 384) {
        int which = b >> 6;
        int i = (b & 63) * 256 + threadIdx.x;
        const float* W = (which == 0) ? w0 : (which == 1) ? w1 : (which == 2) ? w2
                       : (which == 3) ? w3 : (which == 4) ? w4 : w5;
        ushort* Wt = (which == 0) ? o0 : (which == 1) ? o1 : (which == 2) ? o2
                   : (which == 3) ? o3 : (which == 4) ? o4 : o5;
        int fi = i >> 3, e = i & 7;
        int jk = fi >> 6, l = fi & 63;
        int j = jk >> 2, kk = jk & 3;
        int lr = l & 15, lg = l >> 4;
        Wt[i] = f2b(W[(kk * 32 + lg * 8 + e) * 128 + j * 16 + lr]);
    } else if (b < 448) {
        int bb = b - 384;
        int which = bb >> 4;
        const WavSet s = (which == 0) ? s0 : (which == 1) ? s1 : (which == 2) ? s2 : s3;
        int i = (bb & 15) * 256 + threadIdx.x;
        int fi = i >> 3, e = i & 7;
        int jk = fi >> 6, l = fi & 63;
        int jt = jk >> 2, kk = jk & 3;
        int lr = l & 15, lg = l >> 4;
        int c = jt * 16 + lr;
        int m = kk * 32 + lg * 8 + e;
        int vec = c >> 3, h = c & 7;
        const float* vp = (vec == 0) ? s.v0 : (vec == 1) ? s.v1 : (vec == 2) ? s.v2 : s.v3;
        float sv = 0.f;
        if (vp) {
            #pragma unroll
            for (int dd = 0; dd < 16; ++dd)
                sv = fmaf(s.W[m * 128 + h * 16 + dd], vp[h * 16 + dd], sv);
        }
        s.GT[i] = f2b(sv);
        if (i < 32) {
            int cc = i, vv = cc >> 3, hh = cc & 7;
            const float* vq = (vv == 0) ? s.v0 : (vv == 1) ? s.v1 : (vv == 2) ? s.v2 : s.v3;
            float t = 0.f;
            if (vq) {
                #pragma unroll
                for (int dd = 0; dd < 16; ++dd)
                    t = fmaf(s.b[hh * 16 + dd], vq[hh * 16 + dd], t);
            }
            s.bAv[cc] = t;
        }
    } else {
        int bb2 = b - 448;
        int ty = bb2 / EB, bb = bb2 % EB;
        const int* ei = (ty == 0) ? e0 : (ty == 1) ? e1 : e2;
        int e = bb * 256 + threadIdx.x;
        if (e < NEDGE) atomicAdd(deg3 + ty * NNODE + ei[NEDGE + e], 1);
    }
}

// ---------------- persistent MFMA GEMM + optional fused CSR scatter --------
// j-split core (two phases of 4 j-tiles); slim prefetch rawA[8];
// __launch_bounds__(256,3) forces VGPR <= ~170 for 3 blocks/CU.
struct PArgs {
    const void* A;
    const ushort* A2;
    const ushort* WtT;
    const ushort* GT;
    const float* bias;
    const float* bAv;
    ushort* C;
    float* ao0; float* ao1; float* ao2; float* ao3;
    int mode;
};

template<int M0, int M1, int SCAT>
__global__ __launch_bounds__(256, 3) void gemm_persist(
    PArgs g0, PArgs g1, const float* __restrict__ attn, int nt, int N,
    const int* __restrict__ e0, const int* __restrict__ e1,
    const int* __restrict__ e2, int* __restrict__ cur3, int* __restrict__ cols3)
{
    if (SCAT && blockIdx.x >= GEMM_GRID) {
        int bb2 = blockIdx.x - GEMM_GRID;
        int ty = bb2 / EB, bb = bb2 % EB;
        const int* ei = (ty == 0) ? e0 : (ty == 1) ? e1 : e2;
        int e = bb * 256 + threadIdx.x;
        if (e < NEDGE) {
            int d = ei[NEDGE + e];
            int pos = atomicAdd(cur3 + ty * NNODE + d, 1);
            __builtin_nontemporal_store(ei[e], cols3 + (size_t)ty * NEDGE + pos);
        }
        return;
    }

    __shared__ uint4 smem[2560];            // 32KB W + 8KB G
    const int hg = GEMM_GRID >> 1;
    const int half = (blockIdx.x >= hg) ? 1 : 0;
    const PArgs ga = half ? g1 : g0;
    const int MODE = half ? M1 : M0;
    const int b0 = half ? blockIdx.x - hg : blockIdx.x;

    const int tid = threadIdx.x;
    const int l = tid & 63, w = tid >> 6;
    const int lr = l & 15, lg = l >> 4;

    {
        const uint4* ws = reinterpret_cast<const uint4*>(ga.WtT);
        const uint4* gs = reinterpret_cast<const uint4*>(ga.GT);
        #pragma unroll
        for (int i = 0; i < 8; ++i) smem[tid + i * 256] = ws[tid + i * 256];
        #pragma unroll
        for (int i = 0; i < 2; ++i) smem[2048 + tid + i * 256] = gs[tid + i * 256];
    }
    float a0 = 0.f, a1 = 0.f;
    if (MODE == 2) { a0 = attn[0]; a1 = attn[1]; }
    __syncthreads();
    const ushort* WtL = reinterpret_cast<const ushort*>(smem);
    const ushort* GL  = WtL + 16384;

    float bv[8];
    #pragma unroll
    for (int j = 0; j < 8; ++j) bv[j] = ga.bias[j * 16 + lr];
    float bA[2];
    #pragma unroll
    for (int jt = 0; jt < 2; ++jt) bA[jt] = ga.bAv[jt * 16 + lr];

    uint4 rawA[8];

    auto clampr = [&](int row) { return (row < N) ? row : (N - 1); };

    auto load_raw = [&](int t) {
        const int rw0 = t * 128 + w * 32;
        if (MODE == 1) {
            int r = clampr(rw0 + lr);   // row i=0 only
            const float* ap = (const float*)ga.A + (size_t)r * 128 + lg * 8;
            #pragma unroll
            for (int kk = 0; kk < 4; ++kk) {
                rawA[kk * 2]     = *reinterpret_cast<const uint4*>(ap + kk * 32);
                rawA[kk * 2 + 1] = *reinterpret_cast<const uint4*>(ap + kk * 32 + 4);
            }
        } else {
            #pragma unroll
            for (int i = 0; i < 2; ++i) {
                int r = clampr(rw0 + i * 16 + lr);
                const ushort* ap = (const ushort*)ga.A + (size_t)r * 128 + lg * 8;
                #pragma unroll
                for (int kk = 0; kk < 4; ++kk)
                    rawA[i * 4 + kk] = *reinterpret_cast<const uint4*>(ap + kk * 32);
            }
        }
    };

    if (b0 >= nt) return;
    load_raw(b0);

    for (int t = b0; t < nt; t += hg) {
        const int rw0 = t * 128 + w * 32;

        bfrag av_[2][4];
        if (MODE == 0) {
            #pragma unroll
            for (int i = 0; i < 2; ++i)
                #pragma unroll
                for (int kk = 0; kk < 4; ++kk)
                    av_[i][kk] = *reinterpret_cast<bfrag*>(&rawA[i * 4 + kk]);
        } else if (MODE == 1) {
            #pragma unroll
            for (int kk = 0; kk < 4; ++kk) {
                uint4 u = rawA[kk * 2], v = rawA[kk * 2 + 1];
                bfrag fr;
                fr[0] = (short)f2b(__uint_as_float(u.x));
                fr[1] = (short)f2b(__uint_as_float(u.y));
                fr[2] = (short)f2b(__uint_as_float(u.z));
                fr[3] = (short)f2b(__uint_as_float(u.w));
                fr[4] = (short)f2b(__uint_as_float(v.x));
                fr[5] = (short)f2b(__uint_as_float(v.y));
                fr[6] = (short)f2b(__uint_as_float(v.z));
                fr[7] = (short)f2b(__uint_as_float(v.w));
                av_[0][kk] = fr;
            }
            {
                int r = clampr(rw0 + 16 + lr);
                const float* ap = (const float*)ga.A + (size_t)r * 128 + lg * 8;
                uint4 u_[4], v_[4];
                #pragma unroll
                for (int kk = 0; kk < 4; ++kk) {
                    u_[kk] = *reinterpret_cast<const uint4*>(ap + kk * 32);
                    v_[kk] = *reinterpret_cast<const uint4*>(ap + kk * 32 + 4);
                }
                #pragma unroll
                for (int kk = 0; kk < 4; ++kk) {
                    bfrag fr;
                    fr[0] = (short)f2b(__uint_as_float(u_[kk].x));
                    fr[1] = (short)f2b(__uint_as_float(u_[kk].y));
                    fr[2] = (short)f2b(__uint_as_float(u_[kk].z));
                    fr[3] = (short)f2b(__uint_as_float(u_[kk].w));
                    fr[4] = (short)f2b(__uint_as_float(v_[kk].x));
                    fr[5] = (short)f2b(__uint_as_float(v_[kk].y));
                    fr[6] = (short)f2b(__uint_as_float(v_[kk].z));
                    fr[7] = (short)f2b(__uint_as_float(v_[kk].w));
                    av_[1][kk] = fr;
                }
            }
        } else {
            uint4 rawB[8];
            #pragma unroll
            for (int i = 0; i < 2; ++i) {
                int r = clampr(rw0 + i * 16 + lr);
                const ushort* ap2 = ga.A2 + (size_t)r * 128 + lg * 8;
                #pragma unroll
                for (int kk = 0; kk < 4; ++kk)
                    rawB[i * 4 + kk] = *reinterpret_cast<const uint4*>(ap2 + kk * 32);
            }
            #pragma unroll
            for (int i = 0; i < 2; ++i) {
                #pragma unroll
                for (int kk = 0; kk < 4; ++kk) {
                    uint4 ua = rawA[i * 4 + kk];
                    uint4 ub = rawB[i * 4 + kk];
                    unsigned int aa[4] = {ua.x, ua.y, ua.z, ua.w};
                    unsigned int bb[4] = {ub.x, ub.y, ub.z, ub.w};
                    bfrag fr;
                    #pragma unroll
                    for (int q = 0; q < 4; ++q) {
                        float lo = a0 * b2f(aa[q] & 0xffffu) + a1 * b2f(bb[q] & 0xffffu);
                        float hi = a0 * b2f(aa[q] >> 16)     + a1 * b2f(bb[q] >> 16);
                        fr[q * 2]     = (short)f2b(lo);
                        fr[q * 2 + 1] = (short)f2b(hi);
                    }
                    av_[i][kk] = fr;
                }
            }
        }

        if (t + hg < nt) load_raw(t + hg);

        // ---- phase 1: j in [0,4) + alpha tiles ----
        {
            facc accC[2][4], accP[2][2];
            #pragma unroll
            for (int i = 0; i < 2; ++i) {
                #pragma unroll
                for (int j = 0; j < 4; ++j) accC[i][j] = (facc){0.f, 0.f, 0.f, 0.f};
                #pragma unroll
                for (int jt = 0; jt < 2; ++jt) accP[i][jt] = (facc){0.f, 0.f, 0.f, 0.f};
            }
            #pragma unroll
            for (int kk = 0; kk < 4; ++kk) {
                #pragma unroll
                for (int j = 0; j < 4; ++j) {
                    bfrag bfr = *reinterpret_cast<const bfrag*>(WtL + ((j * 4 + kk) * 64 + l) * 8);
                    #pragma unroll
                    for (int i = 0; i < 2; ++i)
                        accC[i][j] = __builtin_amdgcn_mfma_f32_16x16x32_bf16(
                            av_[i][kk], bfr, accC[i][j], 0, 0, 0);
                }
                #pragma unroll
                for (int jt = 0; jt < 2; ++jt) {
                    bfrag gfr = *reinterpret_cast<const bfrag*>(GL + ((jt * 4 + kk) * 64 + l) * 8);
                    #pragma unroll
                    for (int i = 0; i < 2; ++i)
                        accP[i][jt] = __builtin_amdgcn_mfma_f32_16x16x32_bf16(
                            av_[i][kk], gfr, accP[i][jt], 0, 0, 0);
                }
            }
            #pragma unroll
            for (int j = 0; j < 4; ++j) {
                #pragma unroll
                for (int i = 0; i < 2; ++i) {
                    #pragma unroll
                    for (int rr = 0; rr < 4; ++rr) {
                        int row = rw0 + i * 16 + lg * 4 + rr;
                        if (row < N)
                            ga.C[(size_t)row * 128 + j * 16 + lr] = f2b(accC[i][j][rr] + bv[j]);
                    }
                }
            }
            #pragma unroll
            for (int jt = 0; jt < 2; ++jt) {
                int c = jt * 16 + lr;
                int vec = c >> 3, h = c & 7;
                float* ao = (vec == 0) ? ga.ao0 : (vec == 1) ? ga.ao1
                          : (vec == 2) ? ga.ao2 : ga.ao3;
                if (ao == nullptr) continue;
                #pragma unroll
                for (int i = 0; i < 2; ++i) {
                    #pragma unroll
                    for (int rr = 0; rr < 4; ++rr) {
                        int row = rw0 + i * 16 + lg * 4 + rr;
                        if (row < N) ao[row * 8 + h] = accP[i][jt][rr] + bA[jt];
                    }
                }
            }
        }

        // ---- phase 2: j in [4,8) ----
        {
            facc accC[2][4];
            #pragma unroll
            for (int i = 0; i < 2; ++i)
                #pragma unroll
                for (int j = 0; j < 4; ++j) accC[i][j] = (facc){0.f, 0.f, 0.f, 0.f};
            #pragma unroll
            for (int kk = 0; kk < 4; ++kk) {
                #pragma unroll
                for (int j = 0; j < 4; ++j) {
                    bfrag bfr = *reinterpret_cast<const bfrag*>(WtL + (((j + 4) * 4 + kk) * 64 + l) * 8);
                    #pragma unroll
                    for (int i = 0; i < 2; ++i)
                        accC[i][j] = __builtin_amdgcn_mfma_f32_16x16x32_bf16(
                            av_[i][kk], bfr, accC[i][j], 0, 0, 0);
                }
            }
            #pragma unroll
            for (int j = 0; j < 4; ++j) {
                #pragma unroll
                for (int i = 0; i < 2; ++i) {
                    #pragma unroll
                    for (int rr = 0; rr < 4; ++rr) {
                        int row = rw0 + i * 16 + lg * 4 + rr;
                        if (row < N)
                            ga.C[(size_t)row * 128 + (j + 4) * 16 + lr] = f2b(accC[i][j][rr] + bv[j + 4]);
                    }
                }
            }
        }
    }
}

// ---------------- persistent MFMA score (partial colsums, no atomics) ------
__global__ __launch_bounds__(256) void score_persist(
    const ushort* __restrict__ A0, const ushort* __restrict__ A1,
    const ushort* __restrict__ WtT, const float* __restrict__ bias,
    float* __restrict__ part, int nt, int N)
{
    __shared__ uint4 smem[2048];            // 32KB W
    __shared__ float sred[4][256];
    const int tid = threadIdx.x;
    const int l = tid & 63, w = tid >> 6;
    const int lr = l & 15, lg = l >> 4;

    {
        const uint4* ws = reinterpret_cast<const uint4*>(WtT);
        #pragma unroll
        for (int i = 0; i < 8; ++i) smem[tid + i * 256] = ws[tid + i * 256];
    }
    __syncthreads();
    const ushort* WtL = reinterpret_cast<const ushort*>(smem);

    float bv[8];
    #pragma unroll
    for (int j = 0; j < 8; ++j) bv[j] = bias[j * 16 + lr];

    float cs[2][8];
    #pragma unroll
    for (int h = 0; h < 2; ++h)
        #pragma unroll
        for (int j = 0; j < 8; ++j) cs[h][j] = 0.f;

    const int total = 2 * nt;
    for (int t = blockIdx.x; t < total; t += gridDim.x) {
        const int half = (t >= nt) ? 1 : 0;
        const ushort* A = half ? A1 : A0;
        const int bb = half ? t - nt : t;
        const int rw0 = bb * 128 + w * 32;

        bfrag av_[2][4];
        #pragma unroll
        for (int i = 0; i < 2; ++i) {
            int r = rw0 + i * 16 + lr; r = (r < N) ? r : (N - 1);
            const ushort* ap = A + (size_t)r * 128 + lg * 8;
            #pragma unroll
            for (int kk = 0; kk < 4; ++kk)
                av_[i][kk] = *reinterpret_cast<const bfrag*>(ap + kk * 32);
        }

        facc acc[2][8];
        #pragma unroll
        for (int i = 0; i < 2; ++i)
            #pragma unroll
            for (int j = 0; j < 8; ++j) acc[i][j] = (facc){0.f, 0.f, 0.f, 0.f};

        #pragma unroll
        for (int kk = 0; kk < 4; ++kk) {
            #pragma unroll
            for (int j = 0; j < 8; ++j) {
                bfrag bfr = *reinterpret_cast<const bfrag*>(WtL + ((j * 4 + kk) * 64 + l) * 8);
                #pragma unroll
                for (int i = 0; i < 2; ++i)
                    acc[i][j] = __builtin_amdgcn_mfma_f32_16x16x32_bf16(
                        av_[i][kk], bfr, acc[i][j], 0, 0, 0);
            }
        }

        #pragma unroll
        for (int j = 0; j < 8; ++j) {
            float s = 0.f;
            #pragma unroll
            for (int i = 0; i < 2; ++i) {
                #pragma unroll
                for (int r = 0; r < 4; ++r) {
                    int row = rw0 + i * 16 + lg * 4 + r;
                    if (row < N) s += fast_tanh(acc[i][j][r] + bv[j]);
                }
            }
            cs[half][j] += s;
        }
    }

    #pragma unroll
    for (int h = 0; h < 2; ++h)
        #pragma unroll
        for (int j = 0; j < 8; ++j) {
            float s = cs[h][j];
            s += __shfl_xor(s, 16, 64);
            s += __shfl_xor(s, 32, 64);
            if (lg == 0) sred[w][h * 128 + j * 16 + lr] = s;
        }
    __syncthreads();
    float tot = sred[0][tid] + sred[1][tid] + sred[2][tid] + sred[3][tid];
    part[(size_t)blockIdx.x * 256 + tid] = tot;
}

// reduce partials + semantic softmax
__global__ void attn_reduce(const float* __restrict__ part,
                            const float* __restrict__ qv,
                            float* __restrict__ attn, int nb)
{
    __shared__ float sm[256];
    int t = threadIdx.x;
    float s0 = 0.f, s1 = 0.f, s2 = 0.f, s3 = 0.f;
    for (int b = 0; b < nb; b += 4) {
        s0 += part[(size_t)b * 256 + t];
        s1 += part[(size_t)(b + 1) * 256 + t];
        s2 += part[(size_t)(b + 2) * 256 + t];
        s3 += part[(size_t)(b + 3) * 256 + t];
    }
    sm[t] = (s0 + s1 + s2 + s3) * qv[t & 127];
    __syncthreads();
    if (t == 0) {
        float a = 0.f, b = 0.f;
        for (int i = 0; i < 128; ++i) { a += sm[i]; b += sm[128 + i]; }
        a *= (1.0f / 100000.0f);
        b *= (1.0f / 100000.0f);
        float m = fmaxf(a, b);
        float ea = expf(a - m), eb = expf(b - m);
        float inv = 1.f / (ea + eb);
        attn[0] = ea * inv;
        attn[1] = eb * inv;
    }
}

// ---------------- CSR scans (bsum prefix folded into scan_add3) ------------
__global__ __launch_bounds__(1024) void scan_block3(
    const int* __restrict__ deg3, int* __restrict__ offs3, int* __restrict__ bsum3)
{
    __shared__ int sd[1024];
    int ty = blockIdx.x / SB, bb = blockIdx.x % SB;
    const int* deg = deg3 + ty * NNODE;
    int* offs = offs3 + ty * (NNODE + 1);
    int t = threadIdx.x, i = bb * 1024 + t;
    int v = (i < NNODE) ? deg[i] : 0;
    sd[t] = v; __syncthreads();
    for (int o = 1; o < 1024; o <<= 1) {
        int x = (t >= o) ? sd[t - o] : 0;
        __syncthreads();
        sd[t] += x;
        __syncthreads();
    }
    if (i < NNODE) offs[i + 1] = sd[t];
    if (t == 1023) bsum3[ty * 128 + bb] = sd[t];
}

__global__ __launch_bounds__(1024) void scan_add3(
    int* __restrict__ offs3, const int* __restrict__ bsum3, int* __restrict__ cur3)
{
    __shared__ int spref;
    int ty = blockIdx.x / SB, bb = blockIdx.x % SB;
    if (threadIdx.x == 0) {
        int run = 0;
        for (int b = 0; b < bb; ++b) run += bsum3[ty * 128 + b];
        spref = run;
    }
    __syncthreads();
    int boff = spref;
    int* offs = offs3 + ty * (NNODE + 1);
    int* cur = cur3 + ty * NNODE;
    int i = bb * 1024 + threadIdx.x;
    if (i == 0) { offs[0] = 0; cur[0] = 0; }
    if (i < NNODE) {
        int v = offs[i + 1] + boff;
        offs[i + 1] = v;
        if (i + 1 < NNODE) cur[i + 1] = v;
    }
}

// ---------------- gather aggregation: 4 nodes per wave, 4-wide batching ----
struct AggJob {
    const int* offs; const int* cols;
    const float* asrc; const float* adst;
    const ushort* z; ushort* out;
};

__global__ __launch_bounds__(256) void agg_multi(AggJob j0, AggJob j1, AggJob j2)
{
    int jb = blockIdx.x / AGG_BLOCKS;
    const AggJob jj = (jb == 0) ? j0 : (jb == 1) ? j1 : j2;
    int bb = blockIdx.x - jb * AGG_BLOCKS;
    int w = threadIdx.x >> 6;
    int lane = threadIdx.x & 63;
    int quarter = lane >> 4;
    int sl = lane & 15;
    int d = bb * 16 + w * 4 + quarter;    // 6250 * 16 = 100000 exactly
    int h = sl >> 1;                       // 2 lanes per head
    float ad = jj.adst[d * 8 + h];
    int e0 = jj.offs[d], e1 = jj.offs[d + 1];
    float acc0 = 0.f, acc1 = 0.f, acc2 = 0.f, acc3 = 0.f;
    float acc4 = 0.f, acc5 = 0.f, acc6 = 0.f, acc7 = 0.f;
    float psum = 0.f;
    const ushort* zbase = jj.z + sl * 8;
    for (int base = e0; base < e1; base += 4) {
        int idx[4];
        #pragma unroll
        for (int i = 0; i < 4; ++i) {
            int ee = base + i;
            idx[i] = jj.cols[(ee < e1) ? ee : (e1 - 1)];
        }
        float xs[4];
        #pragma unroll
        for (int i = 0; i < 4; ++i) xs[i] = jj.asrc[idx[i] * 8 + h];
        uint4 zv[4];
        #pragma unroll
        for (int i = 0; i < 4; ++i)
            zv[i] = *reinterpret_cast<const uint4*>(zbase + (size_t)idx[i] * 128);
        #pragma unroll
        for (int i = 0; i < 4; ++i) {
            float a = xs[i] + ad;
            a = fmaxf(a, NEG * a);          // leakyrelu == max(a, 0.2a)
            float p = __expf(a);
            p = (base + i < e1) ? p : 0.f;
            acc0 = fmaf(p, b2f(zv[i].x & 0xffffu), acc0);
            acc1 = fmaf(p, b2f(zv[i].x >> 16),     acc1);
            acc2 = fmaf(p, b2f(zv[i].y & 0xffffu), acc2);
            acc3 = fmaf(p, b2f(zv[i].y >> 16),     acc3);
            acc4 = fmaf(p, b2f(zv[i].z & 0xffffu), acc4);
            acc5 = fmaf(p, b2f(zv[i].z >> 16),     acc5);
            acc6 = fmaf(p, b2f(zv[i].w & 0xffffu), acc6);
            acc7 = fmaf(p, b2f(zv[i].w >> 16),     acc7);
            psum += p;
        }
    }
    float inv = 1.f / (psum + 1e-16f);
    uint4 pk;
    pk.x = (unsigned int)f2b(fmaxf(acc0 * inv, 0.f))
         | ((unsigned int)f2b(fmaxf(acc1 * inv, 0.f)) << 16);
    pk.y = (unsigned int)f2b(fmaxf(acc2 * inv, 0.f))
         | ((unsigned int)f2b(fmaxf(acc3 * inv, 0.f)) << 16);
    pk.z = (unsigned int)f2b(fmaxf(acc4 * inv, 0.f))
         | ((unsigned int)f2b(fmaxf(acc5 * inv, 0.f)) << 16);
    pk.w = (unsigned int)f2b(fmaxf(acc6 * inv, 0.f))
         | ((unsigned int)f2b(fmaxf(acc7 * inv, 0.f)) << 16);
    *reinterpret_cast<uint4*>(jj.out + (size_t)d * 128 + sl * 8) = pk;
}

// out[N][8] = mix(XA_,XB_,attn) @ W[128][8] + bias
__global__ __launch_bounds__(256) void final_gemm_mix(
    const ushort* __restrict__ XA_, const ushort* __restrict__ XB_,
    const float* __restrict__ attn, const float* __restrict__ W,
    const float* __restrict__ bias, float* __restrict__ out, int N)
{
    __shared__ float Ws[128][8];
    __shared__ __align__(16) float Xs[32][129];
    int tid = threadIdx.x;
    float a0 = attn[0], a1 = attn[1];
    for (int i = tid; i < 1024; i += 256) Ws[i >> 3][i & 7] = W[i];
    int row0 = blockIdx.x * 32;
    for (int i = tid; i < 512; i += 256) {
        int r = i >> 4, q = i & 15;
        int gr = row0 + r;
        uint4 va = make_uint4(0, 0, 0, 0), vb = make_uint4(0, 0, 0, 0);
        if (gr < N) {
            va = reinterpret_cast<const uint4*>(XA_ + (size_t)gr * 128)[q];
            vb = reinterpret_cast<const uint4*>(XB_ + (size_t)gr * 128)[q];
        }
        int c = q * 8;
        unsigned int ua[4] = {va.x, va.y, va.z, va.w};
        unsigned int ub[4] = {vb.x, vb.y, vb.z, vb.w};
        #pragma unroll
        for (int qq = 0; qq < 4; ++qq) {
            Xs[r][c + qq * 2]     = a0 * b2f(ua[qq] & 0xffffu) + a1 * b2f(ub[qq] & 0xffffu);
            Xs[r][c + qq * 2 + 1] = a0 * b2f(ua[qq] >> 16)     + a1 * b2f(ub[qq] >> 16);
        }
    }
    __syncthreads();
    int r = tid >> 3, o = tid & 7;
    int gr = row0 + r;
    if (gr < N) {
        float s = bias[o];
        #pragma unroll
        for (int k = 0; k < 128; ++k) s = fmaf(Xs[r][k], Ws[k][o], s);
        out[(size_t)gr * 8 + o] = s;
    }
}

extern "C" void kernel_launch(void* const* d_in, const int* in_sizes, int n_in,
                              void* d_out, int out_size, void* d_ws, size_t ws_size,
                              hipStream_t stream) {
    const float* x_paper  = (const float*)d_in[0];
    const float* x_author = (const float*)d_in[1];
    const float* Wp_p = (const float*)d_in[2];
    const float* bp_p = (const float*)d_in[3];
    const float* Wp_a = (const float*)d_in[4];
    const float* bp_a = (const float*)d_in[5];
    const float* as_ap = (const float*)d_in[6];
    const float* ad_ap = (const float*)d_in[7];
    const float* as_pa = (const float*)d_in[8];
    const float* ad_pa = (const float*)d_in[9];
    const float* as_pp = (const float*)d_in[10];
    const float* ad_pp = (const float*)d_in[11];
    const float* Wk   = (const float*)d_in[12];
    const float* bk   = (const float*)d_in[13];
    const float* qv   = (const float*)d_in[14];
    const float* Wout = (const float*)d_in[15];
    const float* bout = (const float*)d_in[16];
    const int* ei_ap = (const int*)d_in[17];
    const int* ei_pa = (const int*)d_in[18];
    const int* ei_pp = (const int*)d_in[19];

    const size_t NB = (size_t)NNODE * 128;   // 12.8M elems
    ushort* Z0 = (ushort*)d_ws;
    ushort* Z1 = Z0 + NB;
    ushort* Z2 = Z1 + NB;
    ushort* Z3 = Z2 + NB;
    ushort* P0 = Z3 + NB;
    ushort* P1 = P0 + NB;
    float* fp = (float*)(P1 + NB);
    float* ap_s = fp; fp += NNODE * 8;
    float* ap_d = fp; fp += NNODE * 8;
    float* pa_s = fp; fp += NNODE * 8;
    float* pa_d = fp; fp += NNODE * 8;
    float* pp_s = fp; fp += NNODE * 8;
    float* pp_d = fp; fp += NNODE * 8;
    float* part = fp; fp += (size_t)SCORE_GRID * 256;
    float* attn = fp; fp += 16;
    float* bAv_p0 = fp; fp += 32;
    float* bAv_a0 = fp; fp += 32;
    float* bAv_p1 = fp; fp += 32;
    float* bAv_a1 = fp; fp += 32;
    ushort* up = (ushort*)fp;
    ushort* WtP0 = up; up += 16384;
    ushort* WtA0 = up; up += 16384;
    ushort* WtP1 = up; up += 16384;
    ushort* WtA1 = up; up += 16384;
    ushort* WtK0 = up; up += 16384;
    ushort* WtK1 = up; up += 16384;
    ushort* G_p0 = up; up += 4096;
    ushort* G_a0 = up; up += 4096;
    ushort* G_p1 = up; up += 4096;
    ushort* G_a1 = up; up += 4096;
    int* ip = (int*)(((size_t)up + 15) & ~(size_t)15);
    int* cols3 = ip; ip += 3 * NEDGE;
    int* offs3 = ip; ip += 3 * (NNODE + 1);
    int* deg3  = ip; ip += 3 * NNODE;
    int* cur3  = ip; ip += 3 * NNODE;
    int* bsum3 = ip; ip += 3 * 128;

    const int* cols_ap = cols3;
    const int* cols_pa = cols3 + NEDGE;
    const int* cols_pp = cols3 + 2 * NEDGE;
    const int* offs_ap = offs3;
    const int* offs_pa = offs3 + (NNODE + 1);
    const int* offs_pp = offs3 + 2 * (NNODE + 1);

    const dim3 blk(256);
    const int nt128 = (NNODE + 127) / 128;        // 782 tiles per matrix
    const int wo = 128 * 128, bo = 128, ao = 128;

    // ---- prep (fused: wt transposes + G + histogram) ----
    hipMemsetAsync(deg3, 0, 3 * NNODE * 4, stream);
    {
        WavSet s0{Wp_p, bp_p, ad_ap, as_pa, as_pp, ad_pp, G_p0, bAv_p0};
        WavSet s1{Wp_a, bp_a, as_ap, ad_pa, nullptr, nullptr, G_a0, bAv_a0};
        WavSet s2{Wp_p + wo, bp_p + bo, ad_ap + ao, as_pp + ao, ad_pp + ao, nullptr, G_p1, bAv_p1};
        WavSet s3{Wp_a + wo, bp_a + bo, as_ap + ao, nullptr, nullptr, nullptr, G_a1, bAv_a1};
        prep_fused<<<448 + 3 * EB, blk, 0, stream>>>(
            Wp_p, Wp_a, Wp_p + wo, Wp_a + wo, Wk, Wk + wo,
            WtP0, WtA0, WtP1, WtA1, WtK0, WtK1,
            s0, s1, s2, s3, ei_ap, ei_pa, ei_pp, deg3);
    }
    scan_block3<<<3 * SB, 1024, 0, stream>>>(deg3, offs3, bsum3);
    scan_add3<<<3 * SB, 1024, 0, stream>>>(offs3, bsum3, cur3);

    // ---------------- Layer 0 (gemm mode1 + fused CSR scatter) -------------
    {
        PArgs gp{x_paper,  nullptr, WtP0, G_p0, bp_p, bAv_p0, Z0, ap_d, pa_s, pp_s, pp_d, 1};
        PArgs ga{x_author, nullptr, WtA0, G_a0, bp_a, bAv_a0, Z1, ap_s, pa_d, nullptr, nullptr, 1};
        gemm_persist<1, 1, 1><<<GEMM_GRID + 3 * EB, blk, 0, stream>>>(
            gp, ga, attn, nt128, NNODE, ei_ap, ei_pa, ei_pp, cur3, cols3);
    }

    {
        AggJob a0{offs_ap, cols_ap, ap_s, ap_d, Z1, Z2};   // out_ap -> Z2
        AggJob a1{offs_pa, cols_pa, pa_s, pa_d, Z0, Z3};   // out_pa = new_xa -> Z3
        AggJob a2{offs_pp, cols_pp, pp_s, pp_d, Z0, P0};   // out_pp -> P0
        agg_multi<<<3 * AGG_BLOCKS, blk, 0, stream>>>(a0, a1, a2);
    }

    score_persist<<<SCORE_GRID, blk, 0, stream>>>(Z2, P0, WtK0, bk, part, nt128, NNODE);
    attn_reduce<<<1, 256, 0, stream>>>(part, qv, attn, SCORE_GRID);

    // ---------------- Layer 1 ----------------  (pa edge type dead here)
    {
        PArgs gp{Z2, P0, WtP1, G_p1, bp_p + bo, bAv_p1, Z0, ap_d, pp_s, pp_d, nullptr, 2}; // A = mix
        PArgs ga{Z3, nullptr, WtA1, G_a1, bp_a + bo, bAv_a1, Z1, ap_s, nullptr, nullptr, nullptr, 0};
        gemm_persist<2, 0, 0><<<GEMM_GRID, blk, 0, stream>>>(
            gp, ga, attn, nt128, NNODE, nullptr, nullptr, nullptr, nullptr, nullptr);
    }

    {
        AggJob a0{offs_ap, cols_ap, ap_s, ap_d, Z1, Z2};   // out_ap -> Z2
        AggJob a1{offs_pp, cols_pp, pp_s, pp_d, Z0, P1};   // out_pp -> P1
        agg_multi<<<2 * AGG_BLOCKS, blk, 0, stream>>>(a0, a1, a1);
    }

    score_persist<<<SCORE_GRID, blk, 0, stream>>>(Z2, P1, WtK1, bk + bo, part, nt128, NNODE);
    attn_reduce<<<1, 256, 0, stream>>>(part, qv + bo, attn, SCORE_GRID);

    final_gemm_mix<<<(NNODE + 31) / 32, blk, 0, stream>>>(Z2, P1, attn, Wout, bout, (float*)d_out, NNODE);
}

// Round 21
// 524.853 us; speedup vs baseline: 1.1810x; 1.1810x over previous
//
#include <hip/hip_runtime.h>

#define NHID 128
#define NHEAD 8
#define NNODE 100000
#define NEDGE 500000
#define NEG 0.2f
#define SCORE_GRID 512
#define GEMM_GRID 512
#define AGG_BLOCKS 6250    // 16 nodes per block (4 waves x 4 nodes)
#define EB ((NEDGE + 255) / 256)
#define SB ((NNODE + 1023) / 1024)

typedef float4 f4;
typedef __attribute__((ext_vector_type(8))) short bfrag;   // 8 bf16 (4 VGPR)
typedef __attribute__((ext_vector_type(4))) float facc;    // 4 f32 acc

__device__ inline float b2f(unsigned int u) {
    return __uint_as_float(u << 16);
}
__device__ inline unsigned short f2b(float f) {
    unsigned int u = __float_as_uint(f);
    unsigned int r = (u + 0x7FFFu + ((u >> 16) & 1u)) >> 16;
    return (unsigned short)r;
}
__device__ inline float fast_tanh(float x) {
    float e = __expf(2.f * x);
    return 1.f - 2.f / (e + 1.f);
}

// ---- prep fused: weight transposes + G-matrices + dst hist ----
struct WavSet {
    const float* W; const float* b;
    const float* v0; const float* v1; const float* v2; const float* v3;
    ushort* GT; float* bAv;
};

__global__ __launch_bounds__(256) void prep_fused(
    const float* __restrict__ w0, const float* __restrict__ w1,
    const float* __restrict__ w2, const float* __restrict__ w3,
    const float* __restrict__ w4, const float* __restrict__ w5,
    ushort* __restrict__ o0, ushort* __restrict__ o1,
    ushort* __restrict__ o2, ushort* __restrict__ o3,
    ushort* __restrict__ o4, ushort* __restrict__ o5,
    WavSet s0, WavSet s1, WavSet s2, WavSet s3,
    const int* __restrict__ e0, const int* __restrict__ e1,
    const int* __restrict__ e2, int* __restrict__ deg3)
{
    const int b = blockIdx.x;
    if (b < 384) {
        int which = b >> 6;
        int i = (b & 63) * 256 + threadIdx.x;
        const float* W = (which == 0) ? w0 : (which == 1) ? w1 : (which == 2) ? w2
                       : (which == 3) ? w3 : (which == 4) ? w4 : w5;
        ushort* Wt = (which == 0) ? o0 : (which == 1) ? o1 : (which == 2) ? o2
                   : (which == 3) ? o3 : (which == 4) ? o4 : o5;
        int fi = i >> 3, e = i & 7;
        int jk = fi >> 6, l = fi & 63;
        int j = jk >> 2, kk = jk & 3;
        int lr = l & 15, lg = l >> 4;
        Wt[i] = f2b(W[(kk * 32 + lg * 8 + e) * 128 + j * 16 + lr]);
    } else if (b < 448) {
        int bb = b - 384;
        int which = bb >> 4;
        const WavSet s = (which == 0) ? s0 : (which == 1) ? s1 : (which == 2) ? s2 : s3;
        int i = (bb & 15) * 256 + threadIdx.x;
        int fi = i >> 3, e = i & 7;
        int jk = fi >> 6, l = fi & 63;
        int jt = jk >> 2, kk = jk & 3;
        int lr = l & 15, lg = l >> 4;
        int c = jt * 16 + lr;
        int m = kk * 32 + lg * 8 + e;
        int vec = c >> 3, h = c & 7;
        const float* vp = (vec == 0) ? s.v0 : (vec == 1) ? s.v1 : (vec == 2) ? s.v2 : s.v3;
        float sv = 0.f;
        if (vp) {
            #pragma unroll
            for (int dd = 0; dd < 16; ++dd)
                sv = fmaf(s.W[m * 128 + h * 16 + dd], vp[h * 16 + dd], sv);
        }
        s.GT[i] = f2b(sv);
        if (i < 32) {
            int cc = i, vv = cc >> 3, hh = cc & 7;
            const float* vq = (vv == 0) ? s.v0 : (vv == 1) ? s.v1 : (vv == 2) ? s.v2 : s.v3;
            float t = 0.f;
            if (vq) {
                #pragma unroll
                for (int dd = 0; dd < 16; ++dd)
                    t = fmaf(s.b[hh * 16 + dd], vq[hh * 16 + dd], t);
            }
            s.bAv[cc] = t;
        }
    } else {
        int bb2 = b - 448;
        int ty = bb2 / EB, bb = bb2 % EB;
        const int* ei = (ty == 0) ? e0 : (ty == 1) ? e1 : e2;
        int e = bb * 256 + threadIdx.x;
        if (e < NEDGE) atomicAdd(deg3 + ty * NNODE + ei[NEDGE + e], 1);
    }
}

// ---------------- persistent MFMA GEMM + optional fused CSR scatter --------
// j-split core (two phases of 4 j-tiles); slim prefetch rawA[8].
struct PArgs {
    const void* A;
    const ushort* A2;
    const ushort* WtT;
    const ushort* GT;
    const float* bias;
    const float* bAv;
    ushort* C;
    float* ao0; float* ao1; float* ao2; float* ao3;
    int mode;
};

template<int M0, int M1, int SCAT>
__global__ __launch_bounds__(256) void gemm_persist(
    PArgs g0, PArgs g1, const float* __restrict__ attn, int nt, int N,
    const int* __restrict__ e0, const int* __restrict__ e1,
    const int* __restrict__ e2, int* __restrict__ cur3, int* __restrict__ cols3)
{
    if (SCAT && blockIdx.x >= GEMM_GRID) {
        int bb2 = blockIdx.x - GEMM_GRID;
        int ty = bb2 / EB, bb = bb2 % EB;
        const int* ei = (ty == 0) ? e0 : (ty == 1) ? e1 : e2;
        int e = bb * 256 + threadIdx.x;
        if (e < NEDGE) {
            int d = ei[NEDGE + e];
            int pos = atomicAdd(cur3 + ty * NNODE + d, 1);
            __builtin_nontemporal_store(ei[e], cols3 + (size_t)ty * NEDGE + pos);
        }
        return;
    }

    __shared__ uint4 smem[2560];            // 32KB W + 8KB G
    const int hg = GEMM_GRID >> 1;
    const int half = (blockIdx.x >= hg) ? 1 : 0;
    const PArgs ga = half ? g1 : g0;
    const int MODE = half ? M1 : M0;
    const int b0 = half ? blockIdx.x - hg : blockIdx.x;

    const int tid = threadIdx.x;
    const int l = tid & 63, w = tid >> 6;
    const int lr = l & 15, lg = l >> 4;

    {
        const uint4* ws = reinterpret_cast<const uint4*>(ga.WtT);
        const uint4* gs = reinterpret_cast<const uint4*>(ga.GT);
        #pragma unroll
        for (int i = 0; i < 8; ++i) smem[tid + i * 256] = ws[tid + i * 256];
        #pragma unroll
        for (int i = 0; i < 2; ++i) smem[2048 + tid + i * 256] = gs[tid + i * 256];
    }
    float a0 = 0.f, a1 = 0.f;
    if (MODE == 2) { a0 = attn[0]; a1 = attn[1]; }
    __syncthreads();
    const ushort* WtL = reinterpret_cast<const ushort*>(smem);
    const ushort* GL  = WtL + 16384;

    float bv[8];
    #pragma unroll
    for (int j = 0; j < 8; ++j) bv[j] = ga.bias[j * 16 + lr];
    float bA[2];
    #pragma unroll
    for (int jt = 0; jt < 2; ++jt) bA[jt] = ga.bAv[jt * 16 + lr];

    uint4 rawA[8];

    auto clampr = [&](int row) { return (row < N) ? row : (N - 1); };

    auto load_raw = [&](int t) {
        const int rw0 = t * 128 + w * 32;
        if (MODE == 1) {
            int r = clampr(rw0 + lr);   // row i=0 only
            const float* ap = (const float*)ga.A + (size_t)r * 128 + lg * 8;
            #pragma unroll
            for (int kk = 0; kk < 4; ++kk) {
                rawA[kk * 2]     = *reinterpret_cast<const uint4*>(ap + kk * 32);
                rawA[kk * 2 + 1] = *reinterpret_cast<const uint4*>(ap + kk * 32 + 4);
            }
        } else {
            #pragma unroll
            for (int i = 0; i < 2; ++i) {
                int r = clampr(rw0 + i * 16 + lr);
                const ushort* ap = (const ushort*)ga.A + (size_t)r * 128 + lg * 8;
                #pragma unroll
                for (int kk = 0; kk < 4; ++kk)
                    rawA[i * 4 + kk] = *reinterpret_cast<const uint4*>(ap + kk * 32);
            }
        }
    };

    if (b0 >= nt) return;
    load_raw(b0);

    for (int t = b0; t < nt; t += hg) {
        const int rw0 = t * 128 + w * 32;

        bfrag av_[2][4];
        if (MODE == 0) {
            #pragma unroll
            for (int i = 0; i < 2; ++i)
                #pragma unroll
                for (int kk = 0; kk < 4; ++kk)
                    av_[i][kk] = *reinterpret_cast<bfrag*>(&rawA[i * 4 + kk]);
        } else if (MODE == 1) {
            #pragma unroll
            for (int kk = 0; kk < 4; ++kk) {
                uint4 u = rawA[kk * 2], v = rawA[kk * 2 + 1];
                bfrag fr;
                fr[0] = (short)f2b(__uint_as_float(u.x));
                fr[1] = (short)f2b(__uint_as_float(u.y));
                fr[2] = (short)f2b(__uint_as_float(u.z));
                fr[3] = (short)f2b(__uint_as_float(u.w));
                fr[4] = (short)f2b(__uint_as_float(v.x));
                fr[5] = (short)f2b(__uint_as_float(v.y));
                fr[6] = (short)f2b(__uint_as_float(v.z));
                fr[7] = (short)f2b(__uint_as_float(v.w));
                av_[0][kk] = fr;
            }
            {
                int r = clampr(rw0 + 16 + lr);
                const float* ap = (const float*)ga.A + (size_t)r * 128 + lg * 8;
                uint4 u_[4], v_[4];
                #pragma unroll
                for (int kk = 0; kk < 4; ++kk) {
                    u_[kk] = *reinterpret_cast<const uint4*>(ap + kk * 32);
                    v_[kk] = *reinterpret_cast<const uint4*>(ap + kk * 32 + 4);
                }
                #pragma unroll
                for (int kk = 0; kk < 4; ++kk) {
                    bfrag fr;
                    fr[0] = (short)f2b(__uint_as_float(u_[kk].x));
                    fr[1] = (short)f2b(__uint_as_float(u_[kk].y));
                    fr[2] = (short)f2b(__uint_as_float(u_[kk].z));
                    fr[3] = (short)f2b(__uint_as_float(u_[kk].w));
                    fr[4] = (short)f2b(__uint_as_float(v_[kk].x));
                    fr[5] = (short)f2b(__uint_as_float(v_[kk].y));
                    fr[6] = (short)f2b(__uint_as_float(v_[kk].z));
                    fr[7] = (short)f2b(__uint_as_float(v_[kk].w));
                    av_[1][kk] = fr;
                }
            }
        } else {
            uint4 rawB[8];
            #pragma unroll
            for (int i = 0; i < 2; ++i) {
                int r = clampr(rw0 + i * 16 + lr);
                const ushort* ap2 = ga.A2 + (size_t)r * 128 + lg * 8;
                #pragma unroll
                for (int kk = 0; kk < 4; ++kk)
                    rawB[i * 4 + kk] = *reinterpret_cast<const uint4*>(ap2 + kk * 32);
            }
            #pragma unroll
            for (int i = 0; i < 2; ++i) {
                #pragma unroll
                for (int kk = 0; kk < 4; ++kk) {
                    uint4 ua = rawA[i * 4 + kk];
                    uint4 ub = rawB[i * 4 + kk];
                    unsigned int aa[4] = {ua.x, ua.y, ua.z, ua.w};
                    unsigned int bb[4] = {ub.x, ub.y, ub.z, ub.w};
                    bfrag fr;
                    #pragma unroll
                    for (int q = 0; q < 4; ++q) {
                        float lo = a0 * b2f(aa[q] & 0xffffu) + a1 * b2f(bb[q] & 0xffffu);
                        float hi = a0 * b2f(aa[q] >> 16)     + a1 * b2f(bb[q] >> 16);
                        fr[q * 2]     = (short)f2b(lo);
                        fr[q * 2 + 1] = (short)f2b(hi);
                    }
                    av_[i][kk] = fr;
                }
            }
        }

        if (t + hg < nt) load_raw(t + hg);

        // ---- phase 1: j in [0,4) + alpha tiles ----
        {
            facc accC[2][4], accP[2][2];
            #pragma unroll
            for (int i = 0; i < 2; ++i) {
                #pragma unroll
                for (int j = 0; j < 4; ++j) accC[i][j] = (facc){0.f, 0.f, 0.f, 0.f};
                #pragma unroll
                for (int jt = 0; jt < 2; ++jt) accP[i][jt] = (facc){0.f, 0.f, 0.f, 0.f};
            }
            #pragma unroll
            for (int kk = 0; kk < 4; ++kk) {
                #pragma unroll
                for (int j = 0; j < 4; ++j) {
                    bfrag bfr = *reinterpret_cast<const bfrag*>(WtL + ((j * 4 + kk) * 64 + l) * 8);
                    #pragma unroll
                    for (int i = 0; i < 2; ++i)
                        accC[i][j] = __builtin_amdgcn_mfma_f32_16x16x32_bf16(
                            av_[i][kk], bfr, accC[i][j], 0, 0, 0);
                }
                #pragma unroll
                for (int jt = 0; jt < 2; ++jt) {
                    bfrag gfr = *reinterpret_cast<const bfrag*>(GL + ((jt * 4 + kk) * 64 + l) * 8);
                    #pragma unroll
                    for (int i = 0; i < 2; ++i)
                        accP[i][jt] = __builtin_amdgcn_mfma_f32_16x16x32_bf16(
                            av_[i][kk], gfr, accP[i][jt], 0, 0, 0);
                }
            }
            #pragma unroll
            for (int j = 0; j < 4; ++j) {
                #pragma unroll
                for (int i = 0; i < 2; ++i) {
                    #pragma unroll
                    for (int rr = 0; rr < 4; ++rr) {
                        int row = rw0 + i * 16 + lg * 4 + rr;
                        if (row < N)
                            ga.C[(size_t)row * 128 + j * 16 + lr] = f2b(accC[i][j][rr] + bv[j]);
                    }
                }
            }
            #pragma unroll
            for (int jt = 0; jt < 2; ++jt) {
                int c = jt * 16 + lr;
                int vec = c >> 3, h = c & 7;
                float* ao = (vec == 0) ? ga.ao0 : (vec == 1) ? ga.ao1
                          : (vec == 2) ? ga.ao2 : ga.ao3;
                if (ao == nullptr) continue;
                #pragma unroll
                for (int i = 0; i < 2; ++i) {
                    #pragma unroll
                    for (int rr = 0; rr < 4; ++rr) {
                        int row = rw0 + i * 16 + lg * 4 + rr;
                        if (row < N) ao[row * 8 + h] = accP[i][jt][rr] + bA[jt];
                    }
                }
            }
        }

        // ---- phase 2: j in [4,8) ----
        {
            facc accC[2][4];
            #pragma unroll
            for (int i = 0; i < 2; ++i)
                #pragma unroll
                for (int j = 0; j < 4; ++j) accC[i][j] = (facc){0.f, 0.f, 0.f, 0.f};
            #pragma unroll
            for (int kk = 0; kk < 4; ++kk) {
                #pragma unroll
                for (int j = 0; j < 4; ++j) {
                    bfrag bfr = *reinterpret_cast<const bfrag*>(WtL + (((j + 4) * 4 + kk) * 64 + l) * 8);
                    #pragma unroll
                    for (int i = 0; i < 2; ++i)
                        accC[i][j] = __builtin_amdgcn_mfma_f32_16x16x32_bf16(
                            av_[i][kk], bfr, accC[i][j], 0, 0, 0);
                }
            }
            #pragma unroll
            for (int j = 0; j < 4; ++j) {
                #pragma unroll
                for (int i = 0; i < 2; ++i) {
                    #pragma unroll
                    for (int rr = 0; rr < 4; ++rr) {
                        int row = rw0 + i * 16 + lg * 4 + rr;
                        if (row < N)
                            ga.C[(size_t)row * 128 + (j + 4) * 16 + lr] = f2b(accC[i][j][rr] + bv[j + 4]);
                    }
                }
            }
        }
    }
}

// ---------------- persistent MFMA score (partial colsums, no atomics) ------
__global__ __launch_bounds__(256) void score_persist(
    const ushort* __restrict__ A0, const ushort* __restrict__ A1,
    const ushort* __restrict__ WtT, const float* __restrict__ bias,
    float* __restrict__ part, int nt, int N)
{
    __shared__ uint4 smem[2048];            // 32KB W
    __shared__ float sred[4][256];
    const int tid = threadIdx.x;
    const int l = tid & 63, w = tid >> 6;
    const int lr = l & 15, lg = l >> 4;

    {
        const uint4* ws = reinterpret_cast<const uint4*>(WtT);
        #pragma unroll
        for (int i = 0; i < 8; ++i) smem[tid + i * 256] = ws[tid + i * 256];
    }
    __syncthreads();
    const ushort* WtL = reinterpret_cast<const ushort*>(smem);

    float bv[8];
    #pragma unroll
    for (int j = 0; j < 8; ++j) bv[j] = bias[j * 16 + lr];

    float cs[2][8];
    #pragma unroll
    for (int h = 0; h < 2; ++h)
        #pragma unroll
        for (int j = 0; j < 8; ++j) cs[h][j] = 0.f;

    const int total = 2 * nt;
    for (int t = blockIdx.x; t < total; t += gridDim.x) {
        const int half = (t >= nt) ? 1 : 0;
        const ushort* A = half ? A1 : A0;
        const int bb = half ? t - nt : t;
        const int rw0 = bb * 128 + w * 32;

        bfrag av_[2][4];
        #pragma unroll
        for (int i = 0; i < 2; ++i) {
            int r = rw0 + i * 16 + lr; r = (r < N) ? r : (N - 1);
            const ushort* ap = A + (size_t)r * 128 + lg * 8;
            #pragma unroll
            for (int kk = 0; kk < 4; ++kk)
                av_[i][kk] = *reinterpret_cast<const bfrag*>(ap + kk * 32);
        }

        facc acc[2][8];
        #pragma unroll
        for (int i = 0; i < 2; ++i)
            #pragma unroll
            for (int j = 0; j < 8; ++j) acc[i][j] = (facc){0.f, 0.f, 0.f, 0.f};

        #pragma unroll
        for (int kk = 0; kk < 4; ++kk) {
            #pragma unroll
            for (int j = 0; j < 8; ++j) {
                bfrag bfr = *reinterpret_cast<const bfrag*>(WtL + ((j * 4 + kk) * 64 + l) * 8);
                #pragma unroll
                for (int i = 0; i < 2; ++i)
                    acc[i][j] = __builtin_amdgcn_mfma_f32_16x16x32_bf16(
                        av_[i][kk], bfr, acc[i][j], 0, 0, 0);
            }
        }

        #pragma unroll
        for (int j = 0; j < 8; ++j) {
            float s = 0.f;
            #pragma unroll
            for (int i = 0; i < 2; ++i) {
                #pragma unroll
                for (int r = 0; r < 4; ++r) {
                    int row = rw0 + i * 16 + lg * 4 + r;
                    if (row < N) s += fast_tanh(acc[i][j][r] + bv[j]);
                }
            }
            cs[half][j] += s;
        }
    }

    #pragma unroll
    for (int h = 0; h < 2; ++h)
        #pragma unroll
        for (int j = 0; j < 8; ++j) {
            float s = cs[h][j];
            s += __shfl_xor(s, 16, 64);
            s += __shfl_xor(s, 32, 64);
            if (lg == 0) sred[w][h * 128 + j * 16 + lr] = s;
        }
    __syncthreads();
    float tot = sred[0][tid] + sred[1][tid] + sred[2][tid] + sred[3][tid];
    part[(size_t)blockIdx.x * 256 + tid] = tot;
}

// reduce partials + semantic softmax
__global__ void attn_reduce(const float* __restrict__ part,
                            const float* __restrict__ qv,
                            float* __restrict__ attn, int nb)
{
    __shared__ float sm[256];
    int t = threadIdx.x;
    float s0 = 0.f, s1 = 0.f, s2 = 0.f, s3 = 0.f;
    for (int b = 0; b < nb; b += 4) {
        s0 += part[(size_t)b * 256 + t];
        s1 += part[(size_t)(b + 1) * 256 + t];
        s2 += part[(size_t)(b + 2) * 256 + t];
        s3 += part[(size_t)(b + 3) * 256 + t];
    }
    sm[t] = (s0 + s1 + s2 + s3) * qv[t & 127];
    __syncthreads();
    if (t == 0) {
        float a = 0.f, b = 0.f;
        for (int i = 0; i < 128; ++i) { a += sm[i]; b += sm[128 + i]; }
        a *= (1.0f / 100000.0f);
        b *= (1.0f / 100000.0f);
        float m = fmaxf(a, b);
        float ea = expf(a - m), eb = expf(b - m);
        float inv = 1.f / (ea + eb);
        attn[0] = ea * inv;
        attn[1] = eb * inv;
    }
}

// ---------------- CSR scans (bsum prefix folded into scan_add3) ------------
__global__ __launch_bounds__(1024) void scan_block3(
    const int* __restrict__ deg3, int* __restrict__ offs3, int* __restrict__ bsum3)
{
    __shared__ int sd[1024];
    int ty = blockIdx.x / SB, bb = blockIdx.x % SB;
    const int* deg = deg3 + ty * NNODE;
    int* offs = offs3 + ty * (NNODE + 1);
    int t = threadIdx.x, i = bb * 1024 + t;
    int v = (i < NNODE) ? deg[i] : 0;
    sd[t] = v; __syncthreads();
    for (int o = 1; o < 1024; o <<= 1) {
        int x = (t >= o) ? sd[t - o] : 0;
        __syncthreads();
        sd[t] += x;
        __syncthreads();
    }
    if (i < NNODE) offs[i + 1] = sd[t];
    if (t == 1023) bsum3[ty * 128 + bb] = sd[t];
}

__global__ __launch_bounds__(1024) void scan_add3(
    int* __restrict__ offs3, const int* __restrict__ bsum3, int* __restrict__ cur3)
{
    __shared__ int spref;
    int ty = blockIdx.x / SB, bb = blockIdx.x % SB;
    if (threadIdx.x == 0) {
        int run = 0;
        for (int b = 0; b < bb; ++b) run += bsum3[ty * 128 + b];
        spref = run;
    }
    __syncthreads();
    int boff = spref;
    int* offs = offs3 + ty * (NNODE + 1);
    int* cur = cur3 + ty * NNODE;
    int i = bb * 1024 + threadIdx.x;
    if (i == 0) { offs[0] = 0; cur[0] = 0; }
    if (i < NNODE) {
        int v = offs[i + 1] + boff;
        offs[i + 1] = v;
        if (i + 1 < NNODE) cur[i + 1] = v;
    }
}

// ---------------- gather aggregation: 4 nodes per wave, 4-wide batching ----
struct AggJob {
    const int* offs; const int* cols;
    const float* asrc; const float* adst;
    const ushort* z; ushort* out;
};

__global__ __launch_bounds__(256) void agg_multi(AggJob j0, AggJob j1, AggJob j2)
{
    int jb = blockIdx.x / AGG_BLOCKS;
    const AggJob jj = (jb == 0) ? j0 : (jb == 1) ? j1 : j2;
    int bb = blockIdx.x - jb * AGG_BLOCKS;
    int w = threadIdx.x >> 6;
    int lane = threadIdx.x & 63;
    int quarter = lane >> 4;
    int sl = lane & 15;
    int d = bb * 16 + w * 4 + quarter;    // 6250 * 16 = 100000 exactly
    int h = sl >> 1;                       // 2 lanes per head
    float ad = jj.adst[d * 8 + h];
    int e0 = jj.offs[d], e1 = jj.offs[d + 1];
    float acc0 = 0.f, acc1 = 0.f, acc2 = 0.f, acc3 = 0.f;
    float acc4 = 0.f, acc5 = 0.f, acc6 = 0.f, acc7 = 0.f;
    float psum = 0.f;
    const ushort* zbase = jj.z + sl * 8;
    for (int base = e0; base < e1; base += 4) {
        int idx[4];
        #pragma unroll
        for (int i = 0; i < 4; ++i) {
            int ee = base + i;
            idx[i] = jj.cols[(ee < e1) ? ee : (e1 - 1)];
        }
        float xs[4];
        #pragma unroll
        for (int i = 0; i < 4; ++i) xs[i] = jj.asrc[idx[i] * 8 + h];
        uint4 zv[4];
        #pragma unroll
        for (int i = 0; i < 4; ++i)
            zv[i] = *reinterpret_cast<const uint4*>(zbase + (size_t)idx[i] * 128);
        #pragma unroll
        for (int i = 0; i < 4; ++i) {
            float a = xs[i] + ad;
            a = fmaxf(a, NEG * a);          // leakyrelu == max(a, 0.2a)
            float p = __expf(a);
            p = (base + i < e1) ? p : 0.f;
            acc0 = fmaf(p, b2f(zv[i].x & 0xffffu), acc0);
            acc1 = fmaf(p, b2f(zv[i].x >> 16),     acc1);
            acc2 = fmaf(p, b2f(zv[i].y & 0xffffu), acc2);
            acc3 = fmaf(p, b2f(zv[i].y >> 16),     acc3);
            acc4 = fmaf(p, b2f(zv[i].z & 0xffffu), acc4);
            acc5 = fmaf(p, b2f(zv[i].z >> 16),     acc5);
            acc6 = fmaf(p, b2f(zv[i].w & 0xffffu), acc6);
            acc7 = fmaf(p, b2f(zv[i].w >> 16),     acc7);
            psum += p;
        }
    }
    float inv = 1.f / (psum + 1e-16f);
    uint4 pk;
    pk.x = (unsigned int)f2b(fmaxf(acc0 * inv, 0.f))
         | ((unsigned int)f2b(fmaxf(acc1 * inv, 0.f)) << 16);
    pk.y = (unsigned int)f2b(fmaxf(acc2 * inv, 0.f))
         | ((unsigned int)f2b(fmaxf(acc3 * inv, 0.f)) << 16);
    pk.z = (unsigned int)f2b(fmaxf(acc4 * inv, 0.f))
         | ((unsigned int)f2b(fmaxf(acc5 * inv, 0.f)) << 16);
    pk.w = (unsigned int)f2b(fmaxf(acc6 * inv, 0.f))
         | ((unsigned int)f2b(fmaxf(acc7 * inv, 0.f)) << 16);
    *reinterpret_cast<uint4*>(jj.out + (size_t)d * 128 + sl * 8) = pk;
}

// out[N][8] = mix(XA_,XB_,attn) @ W[128][8] + bias
__global__ __launch_bounds__(256) void final_gemm_mix(
    const ushort* __restrict__ XA_, const ushort* __restrict__ XB_,
    const float* __restrict__ attn, const float* __restrict__ W,
    const float* __restrict__ bias, float* __restrict__ out, int N)
{
    __shared__ float Ws[128][8];
    __shared__ __align__(16) float Xs[32][129];
    int tid = threadIdx.x;
    float a0 = attn[0], a1 = attn[1];
    for (int i = tid; i < 1024; i += 256) Ws[i >> 3][i & 7] = W[i];
    int row0 = blockIdx.x * 32;
    for (int i = tid; i < 512; i += 256) {
        int r = i >> 4, q = i & 15;
        int gr = row0 + r;
        uint4 va = make_uint4(0, 0, 0, 0), vb = make_uint4(0, 0, 0, 0);
        if (gr < N) {
            va = reinterpret_cast<const uint4*>(XA_ + (size_t)gr * 128)[q];
            vb = reinterpret_cast<const uint4*>(XB_ + (size_t)gr * 128)[q];
        }
        int c = q * 8;
        unsigned int ua[4] = {va.x, va.y, va.z, va.w};
        unsigned int ub[4] = {vb.x, vb.y, vb.z, vb.w};
        #pragma unroll
        for (int qq = 0; qq < 4; ++qq) {
            Xs[r][c + qq * 2]     = a0 * b2f(ua[qq] & 0xffffu) + a1 * b2f(ub[qq] & 0xffffu);
            Xs[r][c + qq * 2 + 1] = a0 * b2f(ua[qq] >> 16)     + a1 * b2f(ub[qq] >> 16);
        }
    }
    __syncthreads();
    int r = tid >> 3, o = tid & 7;
    int gr = row0 + r;
    if (gr < N) {
        float s = bias[o];
        #pragma unroll
        for (int k = 0; k < 128; ++k) s = fmaf(Xs[r][k], Ws[k][o], s);
        out[(size_t)gr * 8 + o] = s;
    }
}

extern "C" void kernel_launch(void* const* d_in, const int* in_sizes, int n_in,
                              void* d_out, int out_size, void* d_ws, size_t ws_size,
                              hipStream_t stream) {
    const float* x_paper  = (const float*)d_in[0];
    const float* x_author = (const float*)d_in[1];
    const float* Wp_p = (const float*)d_in[2];
    const float* bp_p = (const float*)d_in[3];
    const float* Wp_a = (const float*)d_in[4];
    const float* bp_a = (const float*)d_in[5];
    const float* as_ap = (const float*)d_in[6];
    const float* ad_ap = (const float*)d_in[7];
    const float* as_pa = (const float*)d_in[8];
    const float* ad_pa = (const float*)d_in[9];
    const float* as_pp = (const float*)d_in[10];
    const float* ad_pp = (const float*)d_in[11];
    const float* Wk   = (const float*)d_in[12];
    const float* bk   = (const float*)d_in[13];
    const float* qv   = (const float*)d_in[14];
    const float* Wout = (const float*)d_in[15];
    const float* bout = (const float*)d_in[16];
    const int* ei_ap = (const int*)d_in[17];
    const int* ei_pa = (const int*)d_in[18];
    const int* ei_pp = (const int*)d_in[19];

    const size_t NB = (size_t)NNODE * 128;   // 12.8M elems
    ushort* Z0 = (ushort*)d_ws;
    ushort* Z1 = Z0 + NB;
    ushort* Z2 = Z1 + NB;
    ushort* Z3 = Z2 + NB;
    ushort* P0 = Z3 + NB;
    ushort* P1 = P0 + NB;
    float* fp = (float*)(P1 + NB);
    float* ap_s = fp; fp += NNODE * 8;
    float* ap_d = fp; fp += NNODE * 8;
    float* pa_s = fp; fp += NNODE * 8;
    float* pa_d = fp; fp += NNODE * 8;
    float* pp_s = fp; fp += NNODE * 8;
    float* pp_d = fp; fp += NNODE * 8;
    float* part = fp; fp += (size_t)SCORE_GRID * 256;
    float* attn = fp; fp += 16;
    float* bAv_p0 = fp; fp += 32;
    float* bAv_a0 = fp; fp += 32;
    float* bAv_p1 = fp; fp += 32;
    float* bAv_a1 = fp; fp += 32;
    ushort* up = (ushort*)fp;
    ushort* WtP0 = up; up += 16384;
    ushort* WtA0 = up; up += 16384;
    ushort* WtP1 = up; up += 16384;
    ushort* WtA1 = up; up += 16384;
    ushort* WtK0 = up; up += 16384;
    ushort* WtK1 = up; up += 16384;
    ushort* G_p0 = up; up += 4096;
    ushort* G_a0 = up; up += 4096;
    ushort* G_p1 = up; up += 4096;
    ushort* G_a1 = up; up += 4096;
    int* ip = (int*)(((size_t)up + 15) & ~(size_t)15);
    int* cols3 = ip; ip += 3 * NEDGE;
    int* offs3 = ip; ip += 3 * (NNODE + 1);
    int* deg3  = ip; ip += 3 * NNODE;
    int* cur3  = ip; ip += 3 * NNODE;
    int* bsum3 = ip; ip += 3 * 128;

    const int* cols_ap = cols3;
    const int* cols_pa = cols3 + NEDGE;
    const int* cols_pp = cols3 + 2 * NEDGE;
    const int* offs_ap = offs3;
    const int* offs_pa = offs3 + (NNODE + 1);
    const int* offs_pp = offs3 + 2 * (NNODE + 1);

    const dim3 blk(256);
    const int nt128 = (NNODE + 127) / 128;        // 782 tiles per matrix
    const int wo = 128 * 128, bo = 128, ao = 128;

    // ---- prep (fused: wt transposes + G + histogram) ----
    hipMemsetAsync(deg3, 0, 3 * NNODE * 4, stream);
    {
        WavSet s0{Wp_p, bp_p, ad_ap, as_pa, as_pp, ad_pp, G_p0, bAv_p0};
        WavSet s1{Wp_a, bp_a, as_ap, ad_pa, nullptr, nullptr, G_a0, bAv_a0};
        WavSet s2{Wp_p + wo, bp_p + bo, ad_ap + ao, as_pp + ao, ad_pp + ao, nullptr, G_p1, bAv_p1};
        WavSet s3{Wp_a + wo, bp_a + bo, as_ap + ao, nullptr, nullptr, nullptr, G_a1, bAv_a1};
        prep_fused<<<448 + 3 * EB, blk, 0, stream>>>(
            Wp_p, Wp_a, Wp_p + wo, Wp_a + wo, Wk, Wk + wo,
            WtP0, WtA0, WtP1, WtA1, WtK0, WtK1,
            s0, s1, s2, s3, ei_ap, ei_pa, ei_pp, deg3);
    }
    scan_block3<<<3 * SB, 1024, 0, stream>>>(deg3, offs3, bsum3);
    scan_add3<<<3 * SB, 1024, 0, stream>>>(offs3, bsum3, cur3);

    // ---------------- Layer 0 (gemm mode1 + fused CSR scatter) -------------
    {
        PArgs gp{x_paper,  nullptr, WtP0, G_p0, bp_p, bAv_p0, Z0, ap_d, pa_s, pp_s, pp_d, 1};
        PArgs ga{x_author, nullptr, WtA0, G_a0, bp_a, bAv_a0, Z1, ap_s, pa_d, nullptr, nullptr, 1};
        gemm_persist<1, 1, 1><<<GEMM_GRID + 3 * EB, blk, 0, stream>>>(
            gp, ga, attn, nt128, NNODE, ei_ap, ei_pa, ei_pp, cur3, cols3);
    }

    {
        AggJob a0{offs_ap, cols_ap, ap_s, ap_d, Z1, Z2};   // out_ap -> Z2
        AggJob a1{offs_pa, cols_pa, pa_s, pa_d, Z0, Z3};   // out_pa = new_xa -> Z3
        AggJob a2{offs_pp, cols_pp, pp_s, pp_d, Z0, P0};   // out_pp -> P0
        agg_multi<<<3 * AGG_BLOCKS, blk, 0, stream>>>(a0, a1, a2);
    }

    score_persist<<<SCORE_GRID, blk, 0, stream>>>(Z2, P0, WtK0, bk, part, nt128, NNODE);
    attn_reduce<<<1, 256, 0, stream>>>(part, qv, attn, SCORE_GRID);

    // ---------------- Layer 1 ----------------  (pa edge type dead here)
    {
        PArgs gp{Z2, P0, WtP1, G_p1, bp_p + bo, bAv_p1, Z0, ap_d, pp_s, pp_d, nullptr, 2}; // A = mix
        PArgs ga{Z3, nullptr, WtA1, G_a1, bp_a + bo, bAv_a1, Z1, ap_s, nullptr, nullptr, nullptr, 0};
        gemm_persist<2, 0, 0><<<GEMM_GRID, blk, 0, stream>>>(
            gp, ga, attn, nt128, NNODE, nullptr, nullptr, nullptr, nullptr, nullptr);
    }

    {
        AggJob a0{offs_ap, cols_ap, ap_s, ap_d, Z1, Z2};   // out_ap -> Z2
        AggJob a1{offs_pp, cols_pp, pp_s, pp_d, Z0, P1};   // out_pp -> P1
        agg_multi<<<2 * AGG_BLOCKS, blk, 0, stream>>>(a0, a1, a1);
    }

    score_persist<<<SCORE_GRID, blk, 0, stream>>>(Z2, P1, WtK1, bk + bo, part, nt128, NNODE);
    attn_reduce<<<1, 256, 0, stream>>>(part, qv + bo, attn, SCORE_GRID);

    final_gemm_mix<<<(NNODE + 31) / 32, blk, 0, stream>>>(Z2, P1, attn, Wout, bout, (float*)d_out, NNODE);
}